// Round 1
// baseline (5413.241 us; speedup 1.0000x reference)
//
#include <hip/hip_runtime.h>
#include <cstddef>
#include <cstdint>

#define L_SEQ 2048
#define D_MODEL 2048
#define NH 16
#define DH 128
#define M_ROWS 4096   // B * L

// ---------------------------------------------------------------------------
// Generic fp32 GEMM: C[M,N] = A[M,K] @ B[K,N], row-major, tiles 64x64, K-step 16.
// 256 threads, each computes a 4x4 microtile. M,N % 64 == 0, K % 16 == 0.
// ---------------------------------------------------------------------------
__global__ __launch_bounds__(256) void gemm_f32(
    const float* __restrict__ A, const float* __restrict__ B,
    float* __restrict__ C, int M, int N, int K)
{
    __shared__ float As[16][64];   // [k][m]
    __shared__ float Bs[16][64];   // [k][n]
    const int bm = blockIdx.y * 64;
    const int bn = blockIdx.x * 64;
    const int t  = threadIdx.x;
    const int tx = t & 15, ty = t >> 4;
    const int arow = t >> 2;          // 0..63
    const int akk  = (t & 3) << 2;    // 0,4,8,12
    const int bkk  = t >> 4;          // 0..15
    const int bcol = (t & 15) << 2;   // 0..60
    const float* Aptr = A + (size_t)(bm + arow) * K + akk;
    const float* Bptr = B + (size_t)bkk * N + bn + bcol;
    float acc[4][4] = {};
    for (int k0 = 0; k0 < K; k0 += 16) {
        const float4 a4 = *(const float4*)(Aptr + k0);
        const float4 b4 = *(const float4*)(Bptr + (size_t)k0 * N);
        __syncthreads();
        As[akk + 0][arow] = a4.x;
        As[akk + 1][arow] = a4.y;
        As[akk + 2][arow] = a4.z;
        As[akk + 3][arow] = a4.w;
        *(float4*)&Bs[bkk][bcol] = b4;
        __syncthreads();
        #pragma unroll
        for (int kk = 0; kk < 16; ++kk) {
            const float4 a = *(const float4*)&As[kk][ty << 2];
            const float4 b = *(const float4*)&Bs[kk][tx << 2];
            acc[0][0] += a.x*b.x; acc[0][1] += a.x*b.y; acc[0][2] += a.x*b.z; acc[0][3] += a.x*b.w;
            acc[1][0] += a.y*b.x; acc[1][1] += a.y*b.y; acc[1][2] += a.y*b.z; acc[1][3] += a.y*b.w;
            acc[2][0] += a.z*b.x; acc[2][1] += a.z*b.y; acc[2][2] += a.z*b.z; acc[2][3] += a.z*b.w;
            acc[3][0] += a.w*b.x; acc[3][1] += a.w*b.y; acc[3][2] += a.w*b.z; acc[3][3] += a.w*b.w;
        }
    }
    #pragma unroll
    for (int i = 0; i < 4; ++i) {
        float4 o;
        o.x = acc[i][0]; o.y = acc[i][1]; o.z = acc[i][2]; o.w = acc[i][3];
        *(float4*)&C[(size_t)(bm + (ty << 2) + i) * N + bn + (tx << 2)] = o;
    }
}

// ---------------------------------------------------------------------------
// RoPE in-place. T has rows of (nheads*128); one thread per (row, head, d<64).
// ---------------------------------------------------------------------------
__global__ __launch_bounds__(256) void rope_kernel(float* __restrict__ T, int nheads)
{
    const int idx  = blockIdx.x * 256 + threadIdx.x;
    const int d    = idx & 63;
    const int tmp  = idx >> 6;
    const int head = tmp % nheads;
    const int row  = tmp / nheads;
    const int l    = row & (L_SEQ - 1);
    const float inv = powf(10000.0f, -(float)d * (1.0f / 64.0f));
    const float ang = (float)l * inv;
    float s, c;
    sincosf(ang, &s, &c);
    const size_t base = (size_t)row * ((size_t)nheads * DH) + (size_t)head * DH + d;
    const float t1 = T[base];
    const float t2 = T[base + 64];
    T[base]      = t1 * c - t2 * s;
    T[base + 64] = t2 * c + t1 * s;
}

// ---------------------------------------------------------------------------
// lam = sigmoid(x @ Wl + bl). One thread per (m, h). Wl is tiny (L2-resident).
// ---------------------------------------------------------------------------
__global__ __launch_bounds__(256) void lam_kernel(
    const float* __restrict__ X, const float* __restrict__ Wl,
    const float* __restrict__ bl, float* __restrict__ Lam)
{
    const int idx = blockIdx.x * 256 + threadIdx.x;   // 65536 total
    const int hh  = idx & 15;
    const int m   = idx >> 4;
    const float* xr = X + (size_t)m * D_MODEL;
    float acc = 0.0f;
    for (int d = 0; d < D_MODEL; d += 4) {
        const float4 xv = *(const float4*)&xr[d];
        acc += xv.x * Wl[(d + 0) * NH + hh];
        acc += xv.y * Wl[(d + 1) * NH + hh];
        acc += xv.z * Wl[(d + 2) * NH + hh];
        acc += xv.w * Wl[(d + 3) * NH + hh];
    }
    acc += bl[hh];
    Lam[idx] = 1.0f / (1.0f + expf(-acc));
}

// ---------------------------------------------------------------------------
// Differential causal flash attention.
// Grid: (L/16, NH, B). Block: 512 thr = 8 waves = (p in {0,1}) x (4 slots).
// Each wave: 4 q-rows, online softmax, ctx dims (2*lane, 2*lane+1) in regs.
// 32-key tiles of K,V staged in LDS (stride 132 breaks bank aliasing).
// p=1 ctx handed to p=0 wave through LDS; writes out = ctx0 - lam*ctx1.
// ---------------------------------------------------------------------------
__global__ __launch_bounds__(512) void attn_kernel(
    const float* __restrict__ Q, const float* __restrict__ Kg,
    const float* __restrict__ Vg, const float* __restrict__ Lam,
    float* __restrict__ OutPre)
{
    __shared__ float k_sh[32 * 132];
    __shared__ float v_sh[32 * 132];
    __shared__ float q_sh[8 * 512];      // per wave: 4 rows x 128
    __shared__ float p_sh[8 * 32 * 4];   // per wave: 32 keys x 4 rows

    const int h  = blockIdx.y;
    const int b  = blockIdx.z;
    const int r0 = blockIdx.x * 16;
    const int t  = threadIdx.x;
    const int w    = t >> 6;     // wave 0..7
    const int lane = t & 63;
    const int slot = w & 3;
    const int p    = w >> 2;     // 0 or 1
    const int rbase = r0 + slot * 4;

    // stage this wave's 4 q rows into LDS
    {
        const int i  = lane >> 4;
        const int d0 = (lane & 15) << 3;
        const size_t qoff = ((size_t)(b * L_SEQ + rbase + i)) * 4096
                          + (size_t)(2 * h + p) * DH + d0;
        *(float4*)&q_sh[w * 512 + i * 128 + d0]     = *(const float4*)&Q[qoff];
        *(float4*)&q_sh[w * 512 + i * 128 + d0 + 4] = *(const float4*)&Q[qoff + 4];
    }

    float cx[4]   = {0.f, 0.f, 0.f, 0.f};
    float cy[4]   = {0.f, 0.f, 0.f, 0.f};
    float mrow[4] = {-1e30f, -1e30f, -1e30f, -1e30f};
    float lrow[4] = {0.f, 0.f, 0.f, 0.f};
    const float scale = 0.08838834764831845f;  // 1/sqrt(128)

    const int jrow = t >> 4;           // staging row 0..31
    const int jd0  = (t & 15) << 3;
    const size_t kvbh = (size_t)b * L_SEQ * D_MODEL + (size_t)h * DH;

    const int kj = lane & 31;          // key within tile
    const int hhalf = lane >> 5;       // which 64-dim half of the dot
    const int ktmax = r0 >> 5;

    for (int kt = 0; kt <= ktmax; ++kt) {
        const size_t goff = kvbh + (size_t)(kt * 32 + jrow) * D_MODEL + jd0;
        const float4 ka = *(const float4*)&Kg[goff];
        const float4 kb = *(const float4*)&Kg[goff + 4];
        const float4 va = *(const float4*)&Vg[goff];
        const float4 vb = *(const float4*)&Vg[goff + 4];
        __syncthreads();
        *(float4*)&k_sh[jrow * 132 + jd0]     = ka;
        *(float4*)&k_sh[jrow * 132 + jd0 + 4] = kb;
        *(float4*)&v_sh[jrow * 132 + jd0]     = va;
        *(float4*)&v_sh[jrow * 132 + jd0 + 4] = vb;
        __syncthreads();

        // scores: lane -> (key kj, dim-half hhalf); 4 rows per wave
        float s0 = 0.f, s1 = 0.f, s2 = 0.f, s3 = 0.f;
        const float* krow = &k_sh[kj * 132 + hhalf * 64];
        const float* qb   = &q_sh[w * 512 + hhalf * 64];
        #pragma unroll
        for (int c = 0; c < 16; ++c) {
            const float4 kv = *(const float4*)&krow[c * 4];
            const float4 q0 = *(const float4*)&qb[c * 4];
            const float4 q1 = *(const float4*)&qb[128 + c * 4];
            const float4 q2 = *(const float4*)&qb[256 + c * 4];
            const float4 q3 = *(const float4*)&qb[384 + c * 4];
            s0 += q0.x*kv.x + q0.y*kv.y + q0.z*kv.z + q0.w*kv.w;
            s1 += q1.x*kv.x + q1.y*kv.y + q1.z*kv.z + q1.w*kv.w;
            s2 += q2.x*kv.x + q2.y*kv.y + q2.z*kv.z + q2.w*kv.w;
            s3 += q3.x*kv.x + q3.y*kv.y + q3.z*kv.z + q3.w*kv.w;
        }
        // combine the two 64-dim halves
        s0 += __shfl_xor(s0, 32);
        s1 += __shfl_xor(s1, 32);
        s2 += __shfl_xor(s2, 32);
        s3 += __shfl_xor(s3, 32);

        const int jg = kt * 32 + kj;
        float sv[4] = {s0, s1, s2, s3};
        #pragma unroll
        for (int i = 0; i < 4; ++i) {
            const int r = rbase + i;
            float s = (jg <= r) ? sv[i] * scale : -1e9f;
            float mx = s;
            #pragma unroll
            for (int off = 16; off >= 1; off >>= 1)
                mx = fmaxf(mx, __shfl_xor(mx, off));
            const float mnew = fmaxf(mrow[i], mx);
            const float pj = __expf(s - mnew);
            float ps = pj;
            #pragma unroll
            for (int off = 16; off >= 1; off >>= 1)
                ps += __shfl_xor(ps, off);
            const float alpha = __expf(mrow[i] - mnew);
            cx[i] *= alpha; cy[i] *= alpha;
            lrow[i] = lrow[i] * alpha + ps;
            mrow[i] = mnew;
            if (hhalf == 0) p_sh[w * 128 + kj * 4 + i] = pj;
        }

        // ctx += P^T @ V ; lane owns dims (2*lane, 2*lane+1)
        #pragma unroll 8
        for (int j = 0; j < 32; ++j) {
            const float4 p4 = *(const float4*)&p_sh[w * 128 + j * 4];
            const float2 vv = *(const float2*)&v_sh[j * 132 + 2 * lane];
            cx[0] += p4.x * vv.x; cy[0] += p4.x * vv.y;
            cx[1] += p4.y * vv.x; cy[1] += p4.y * vv.y;
            cx[2] += p4.z * vv.x; cy[2] += p4.z * vv.y;
            cx[3] += p4.w * vv.x; cy[3] += p4.w * vv.y;
        }
    }

    // combine p=0 and p=1: out = ctx0 - lam * ctx1
    float* comb = q_sh;   // reuse (2048 floats needed, q_sh has 4096)
    __syncthreads();
    if (p == 1) {
        #pragma unroll
        for (int i = 0; i < 4; ++i) {
            const float invl = 1.0f / lrow[i];
            float2 o; o.x = cx[i] * invl; o.y = cy[i] * invl;
            *(float2*)&comb[(slot * 4 + i) * 128 + 2 * lane] = o;
        }
    }
    __syncthreads();
    if (p == 0) {
        #pragma unroll
        for (int i = 0; i < 4; ++i) {
            const int r = rbase + i;
            const float invl = 1.0f / lrow[i];
            const float lamv = Lam[(size_t)(b * L_SEQ + r) * NH + h];
            const float2 c1 = *(const float2*)&comb[(slot * 4 + i) * 128 + 2 * lane];
            float2 o;
            o.x = cx[i] * invl - lamv * c1.x;
            o.y = cy[i] * invl - lamv * c1.y;
            *(float2*)&OutPre[(size_t)(b * L_SEQ + r) * D_MODEL + (size_t)h * DH + 2 * lane] = o;
        }
    }
}

// ---------------------------------------------------------------------------
extern "C" void kernel_launch(void* const* d_in, const int* in_sizes, int n_in,
                              void* d_out, int out_size, void* d_ws, size_t ws_size,
                              hipStream_t stream)
{
    const float* x  = (const float*)d_in[0];
    const float* Wq = (const float*)d_in[1];
    const float* Wk = (const float*)d_in[2];
    const float* Wv = (const float*)d_in[3];
    const float* Wl = (const float*)d_in[4];
    const float* bl = (const float*)d_in[5];
    const float* Wo = (const float*)d_in[6];
    float* out = (float*)d_out;

    float* ws = (float*)d_ws;
    float* Qb     = ws;                                   // 4096 * 4096
    float* Kb     = Qb  + (size_t)M_ROWS * 4096;          // 4096 * 2048
    float* Vb     = Kb  + (size_t)M_ROWS * D_MODEL;       // 4096 * 2048
    float* LamB   = Vb  + (size_t)M_ROWS * D_MODEL;       // 4096 * 16
    float* OutPre = LamB + (size_t)M_ROWS * NH;           // 4096 * 2048
    (void)ws_size; (void)in_sizes; (void)n_in; (void)out_size;

    // projections
    gemm_f32<<<dim3(4096 / 64, M_ROWS / 64), 256, 0, stream>>>(x, Wq, Qb, M_ROWS, 4096, D_MODEL);
    gemm_f32<<<dim3(D_MODEL / 64, M_ROWS / 64), 256, 0, stream>>>(x, Wk, Kb, M_ROWS, D_MODEL, D_MODEL);
    gemm_f32<<<dim3(D_MODEL / 64, M_ROWS / 64), 256, 0, stream>>>(x, Wv, Vb, M_ROWS, D_MODEL, D_MODEL);
    lam_kernel<<<(M_ROWS * NH) / 256, 256, 0, stream>>>(x, Wl, bl, LamB);

    // RoPE on q (32 head-pairs) and k (16 heads)
    rope_kernel<<<(M_ROWS * 32 * 64) / 256, 256, 0, stream>>>(Qb, 32);
    rope_kernel<<<(M_ROWS * 16 * 64) / 256, 256, 0, stream>>>(Kb, 16);

    // differential causal attention -> OutPre (B, L, D)
    attn_kernel<<<dim3(L_SEQ / 16, NH, 2), 512, 0, stream>>>(Qb, Kb, Vb, LamB, OutPre);

    // final projection
    gemm_f32<<<dim3(D_MODEL / 64, M_ROWS / 64), 256, 0, stream>>>(OutPre, Wo, out, M_ROWS, D_MODEL, D_MODEL);
}

// Round 2
// 2822.158 us; speedup vs baseline: 1.9181x; 1.9181x over previous
//
#include <hip/hip_runtime.h>
#include <cstddef>
#include <cstdint>

#define L_SEQ 2048
#define D_MODEL 2048
#define NH 16
#define DH 128
#define M_ROWS 4096   // B * L

// ---------------------------------------------------------------------------
// bf16 helpers (storage type: ushort)
// ---------------------------------------------------------------------------
__device__ __forceinline__ ushort f2bf(float f) {
    union { float f; uint32_t u; } v; v.f = f;
    const uint32_t u = v.u;
    return (ushort)((u + 0x7fffu + ((u >> 16) & 1u)) >> 16);   // RNE
}
__device__ __forceinline__ float bf2f(ushort h) {
    union { uint32_t u; float f; } v; v.u = ((uint32_t)h) << 16; return v.f;
}
__device__ __forceinline__ float2 bf2f2(uint32_t u) {
    union { uint32_t u; float f; } lo, hi;
    lo.u = u << 16; hi.u = u & 0xffff0000u;
    return make_float2(lo.f, hi.f);
}

__device__ __forceinline__ void gld_lds16(const void* g, void* l) {
    __builtin_amdgcn_global_load_lds(
        (const __attribute__((address_space(1))) void*)g,
        (__attribute__((address_space(3))) void*)l, 16, 0, 0);
}

typedef __bf16  bf16x8 __attribute__((ext_vector_type(8)));
typedef float   f32x4  __attribute__((ext_vector_type(4)));

// ---------------------------------------------------------------------------
// fp32 -> bf16 elementwise (8 elems/thread)
// ---------------------------------------------------------------------------
__global__ __launch_bounds__(256) void cvt_bf16(
    const float* __restrict__ in, ushort* __restrict__ out)
{
    const int i = (blockIdx.x * 256 + threadIdx.x) * 8;
    const float4 a = *(const float4*)&in[i];
    const float4 b = *(const float4*)&in[i + 4];
    uint4 o;
    o.x = (uint)f2bf(a.x) | ((uint)f2bf(a.y) << 16);
    o.y = (uint)f2bf(a.z) | ((uint)f2bf(a.w) << 16);
    o.z = (uint)f2bf(b.x) | ((uint)f2bf(b.y) << 16);
    o.w = (uint)f2bf(b.z) | ((uint)f2bf(b.w) << 16);
    *(uint4*)&out[i] = o;
}

// ---------------------------------------------------------------------------
// W [K,N] fp32 -> Wt [N,K] bf16 (32x32 LDS tile transpose)
// ---------------------------------------------------------------------------
__global__ __launch_bounds__(256) void transpose_cvt(
    const float* __restrict__ W, ushort* __restrict__ Wt, int K, int N)
{
    __shared__ float tile[32][33];
    const int n0 = blockIdx.x * 32, k0 = blockIdx.y * 32;
    const int t = threadIdx.x;
    const int r = t >> 3;          // 0..31
    const int c4 = (t & 7) * 4;    // 0..28
    const float4 v = *(const float4*)&W[(size_t)(k0 + r) * N + n0 + c4];
    tile[r][c4 + 0] = v.x; tile[r][c4 + 1] = v.y;
    tile[r][c4 + 2] = v.z; tile[r][c4 + 3] = v.w;
    __syncthreads();
    ushort4 o;
    o.x = f2bf(tile[c4 + 0][r]);
    o.y = f2bf(tile[c4 + 1][r]);
    o.z = f2bf(tile[c4 + 2][r]);
    o.w = f2bf(tile[c4 + 3][r]);
    *(ushort4*)&Wt[(size_t)(n0 + r) * K + k0 + c4] = o;
}

// ---------------------------------------------------------------------------
// bf16 MFMA GEMM (m97 recipe): C[M,N] = A[M,K] . Bt[N,K]^T
// 128x128 tile, BK=32, 256 thr (4 waves, each 64x64 quadrant, 4x4 MFMA tiles)
// global_load_lds width-16 staging; OUT_BF16 selects output dtype.
// ---------------------------------------------------------------------------
template <int OUT_BF16>
__global__ __launch_bounds__(256) void gemm_bf16(
    const ushort* __restrict__ A, const ushort* __restrict__ Bt,
    void* __restrict__ Cv, int M, int N, int K)
{
    __shared__ __align__(16) ushort As[128 * 32];
    __shared__ __align__(16) ushort Bs[128 * 32];
    const int bm = blockIdx.y * 128;
    const int bn = blockIdx.x * 128;
    const int t = threadIdx.x;
    const int w = t >> 6, lane = t & 63;
    const int wm = (w & 1) * 64;   // wave row-quadrant
    const int wn = (w >> 1) * 64;  // wave col-quadrant

    // staging: slot s (0..511) -> row s>>2, col-chunk (s&3)*8 ; s = t, t+256
    const int srow = t >> 2;
    const int scol = (t & 3) * 8;
    const ushort* Ag  = A  + (size_t)(bm + srow) * K + scol;
    const ushort* Ag2 = A  + (size_t)(bm + 64 + srow) * K + scol;
    const ushort* Bg  = Bt + (size_t)(bn + srow) * K + scol;
    const ushort* Bg2 = Bt + (size_t)(bn + 64 + srow) * K + scol;
    ushort* Asl  = &As[(size_t)t * 8];
    ushort* Asl2 = &As[(size_t)(t + 256) * 8];
    ushort* Bsl  = &Bs[(size_t)t * 8];
    ushort* Bsl2 = &Bs[(size_t)(t + 256) * 8];

    const int fr = lane & 15;          // m (or n) within 16-tile
    const int fq = (lane >> 4) * 8;    // k offset of the 8-elem fragment
    const ushort* Abase = &As[(size_t)(wm + fr) * 32 + fq];
    const ushort* Bbase = &Bs[(size_t)(wn + fr) * 32 + fq];

    f32x4 acc[4][4] = {};

    for (int k0 = 0; k0 < K; k0 += 32) {
        __syncthreads();
        gld_lds16(Ag + k0, Asl);
        gld_lds16(Ag2 + k0, Asl2);
        gld_lds16(Bg + k0, Bsl);
        gld_lds16(Bg2 + k0, Bsl2);
        __syncthreads();
        bf16x8 a[4], b[4];
        #pragma unroll
        for (int i = 0; i < 4; ++i) {
            a[i] = *(const bf16x8*)(Abase + (size_t)i * 16 * 32);
            b[i] = *(const bf16x8*)(Bbase + (size_t)i * 16 * 32);
        }
        #pragma unroll
        for (int mt = 0; mt < 4; ++mt)
            #pragma unroll
            for (int nt = 0; nt < 4; ++nt)
                acc[mt][nt] = __builtin_amdgcn_mfma_f32_16x16x32_bf16(
                    a[mt], b[nt], acc[mt][nt], 0, 0, 0);
    }

    // epilogue: C/D map col=lane&15, row=(lane>>4)*4+reg  [m89-verified]
    const int crow = (lane >> 4) * 4;
    const int ccol = lane & 15;
    #pragma unroll
    for (int mt = 0; mt < 4; ++mt) {
        #pragma unroll
        for (int nt = 0; nt < 4; ++nt) {
            #pragma unroll
            for (int reg = 0; reg < 4; ++reg) {
                const size_t row = bm + wm + mt * 16 + crow + reg;
                const size_t col = bn + wn + nt * 16 + ccol;
                if (OUT_BF16) {
                    ((ushort*)Cv)[row * N + col] = f2bf(acc[mt][nt][reg]);
                } else {
                    ((float*)Cv)[row * N + col] = acc[mt][nt][reg];
                }
            }
        }
    }
}

// ---------------------------------------------------------------------------
// RoPE in-place on bf16. One thread per (row, head, d<64).
// ---------------------------------------------------------------------------
__global__ __launch_bounds__(256) void rope_bf16(ushort* __restrict__ T, int nheads)
{
    const int idx  = blockIdx.x * 256 + threadIdx.x;
    const int d    = idx & 63;
    const int tmp  = idx >> 6;
    const int head = tmp % nheads;
    const int row  = tmp / nheads;
    const int l    = row & (L_SEQ - 1);
    const float inv = powf(10000.0f, -(float)d * (1.0f / 64.0f));
    const float ang = (float)l * inv;
    float s, c;
    sincosf(ang, &s, &c);
    const size_t base = (size_t)row * ((size_t)nheads * DH) + (size_t)head * DH + d;
    const float t1 = bf2f(T[base]);
    const float t2 = bf2f(T[base + 64]);
    T[base]      = f2bf(t1 * c - t2 * s);
    T[base + 64] = f2bf(t2 * c + t1 * s);
}

// ---------------------------------------------------------------------------
// lam = sigmoid(x @ Wl + bl) (x stays fp32)
// ---------------------------------------------------------------------------
__global__ __launch_bounds__(256) void lam_kernel(
    const float* __restrict__ X, const float* __restrict__ Wl,
    const float* __restrict__ bl, float* __restrict__ Lam)
{
    const int idx = blockIdx.x * 256 + threadIdx.x;   // 65536 total
    const int hh  = idx & 15;
    const int m   = idx >> 4;
    const float* xr = X + (size_t)m * D_MODEL;
    float acc = 0.0f;
    for (int d = 0; d < D_MODEL; d += 4) {
        const float4 xv = *(const float4*)&xr[d];
        acc += xv.x * Wl[(d + 0) * NH + hh];
        acc += xv.y * Wl[(d + 1) * NH + hh];
        acc += xv.z * Wl[(d + 2) * NH + hh];
        acc += xv.w * Wl[(d + 3) * NH + hh];
    }
    acc += bl[hh];
    Lam[idx] = 1.0f / (1.0f + expf(-acc));
}

// ---------------------------------------------------------------------------
// Differential causal flash attention (bf16 in, bf16 out, fp32 math).
// Grid: (L/16, NH, B). Block: 512 thr = 8 waves = (p in {0,1}) x (4 slots).
// ---------------------------------------------------------------------------
__global__ __launch_bounds__(512) void attn_kernel(
    const ushort* __restrict__ Q, const ushort* __restrict__ Kg,
    const ushort* __restrict__ Vg, const float* __restrict__ Lam,
    ushort* __restrict__ OutB)
{
    __shared__ float k_sh[32 * 132];
    __shared__ float v_sh[32 * 132];
    __shared__ float q_sh[8 * 512];      // per wave: 4 rows x 128
    __shared__ float p_sh[8 * 32 * 4];   // per wave: 32 keys x 4 rows

    const int h  = blockIdx.y;
    const int b  = blockIdx.z;
    const int r0 = blockIdx.x * 16;
    const int t  = threadIdx.x;
    const int w    = t >> 6;     // wave 0..7
    const int lane = t & 63;
    const int slot = w & 3;
    const int p    = w >> 2;     // 0 or 1
    const int rbase = r0 + slot * 4;

    // stage this wave's 4 q rows into LDS (bf16 -> f32)
    {
        const int i  = lane >> 4;
        const int d0 = (lane & 15) << 3;
        const size_t qoff = ((size_t)(b * L_SEQ + rbase + i)) * 4096
                          + (size_t)(2 * h + p) * DH + d0;
        const uint4 qv = *(const uint4*)&Q[qoff];
        const float2 f0 = bf2f2(qv.x), f1 = bf2f2(qv.y);
        const float2 f2v = bf2f2(qv.z), f3 = bf2f2(qv.w);
        float* qd = &q_sh[w * 512 + i * 128 + d0];
        qd[0] = f0.x; qd[1] = f0.y; qd[2] = f1.x; qd[3] = f1.y;
        qd[4] = f2v.x; qd[5] = f2v.y; qd[6] = f3.x; qd[7] = f3.y;
    }

    float cx[4]   = {0.f, 0.f, 0.f, 0.f};
    float cy[4]   = {0.f, 0.f, 0.f, 0.f};
    float mrow[4] = {-1e30f, -1e30f, -1e30f, -1e30f};
    float lrow[4] = {0.f, 0.f, 0.f, 0.f};
    const float scale = 0.08838834764831845f;  // 1/sqrt(128)

    const int jrow = t >> 4;           // staging row 0..31
    const int jd0  = (t & 15) << 3;
    const size_t kvbh = (size_t)b * L_SEQ * D_MODEL + (size_t)h * DH;

    const int kj = lane & 31;          // key within tile
    const int hhalf = lane >> 5;       // which 64-dim half of the dot
    const int ktmax = r0 >> 5;

    for (int kt = 0; kt <= ktmax; ++kt) {
        const size_t goff = kvbh + (size_t)(kt * 32 + jrow) * D_MODEL + jd0;
        const uint4 k8 = *(const uint4*)&Kg[goff];
        const uint4 v8 = *(const uint4*)&Vg[goff];
        __syncthreads();
        {
            float* kd = &k_sh[jrow * 132 + jd0];
            float* vd = &v_sh[jrow * 132 + jd0];
            float2 u;
            u = bf2f2(k8.x); kd[0] = u.x; kd[1] = u.y;
            u = bf2f2(k8.y); kd[2] = u.x; kd[3] = u.y;
            u = bf2f2(k8.z); kd[4] = u.x; kd[5] = u.y;
            u = bf2f2(k8.w); kd[6] = u.x; kd[7] = u.y;
            u = bf2f2(v8.x); vd[0] = u.x; vd[1] = u.y;
            u = bf2f2(v8.y); vd[2] = u.x; vd[3] = u.y;
            u = bf2f2(v8.z); vd[4] = u.x; vd[5] = u.y;
            u = bf2f2(v8.w); vd[6] = u.x; vd[7] = u.y;
        }
        __syncthreads();

        // scores: lane -> (key kj, dim-half hhalf); 4 rows per wave
        float s0 = 0.f, s1 = 0.f, s2 = 0.f, s3 = 0.f;
        const float* krow = &k_sh[kj * 132 + hhalf * 64];
        const float* qb   = &q_sh[w * 512 + hhalf * 64];
        #pragma unroll
        for (int c = 0; c < 16; ++c) {
            const float4 kv = *(const float4*)&krow[c * 4];
            const float4 q0 = *(const float4*)&qb[c * 4];
            const float4 q1 = *(const float4*)&qb[128 + c * 4];
            const float4 q2 = *(const float4*)&qb[256 + c * 4];
            const float4 q3 = *(const float4*)&qb[384 + c * 4];
            s0 += q0.x*kv.x + q0.y*kv.y + q0.z*kv.z + q0.w*kv.w;
            s1 += q1.x*kv.x + q1.y*kv.y + q1.z*kv.z + q1.w*kv.w;
            s2 += q2.x*kv.x + q2.y*kv.y + q2.z*kv.z + q2.w*kv.w;
            s3 += q3.x*kv.x + q3.y*kv.y + q3.z*kv.z + q3.w*kv.w;
        }
        s0 += __shfl_xor(s0, 32);
        s1 += __shfl_xor(s1, 32);
        s2 += __shfl_xor(s2, 32);
        s3 += __shfl_xor(s3, 32);

        const int jg = kt * 32 + kj;
        float sv[4] = {s0, s1, s2, s3};
        #pragma unroll
        for (int i = 0; i < 4; ++i) {
            const int r = rbase + i;
            float s = (jg <= r) ? sv[i] * scale : -1e9f;
            float mx = s;
            #pragma unroll
            for (int off = 16; off >= 1; off >>= 1)
                mx = fmaxf(mx, __shfl_xor(mx, off));
            const float mnew = fmaxf(mrow[i], mx);
            const float pj = __expf(s - mnew);
            float ps = pj;
            #pragma unroll
            for (int off = 16; off >= 1; off >>= 1)
                ps += __shfl_xor(ps, off);
            const float alpha = __expf(mrow[i] - mnew);
            cx[i] *= alpha; cy[i] *= alpha;
            lrow[i] = lrow[i] * alpha + ps;
            mrow[i] = mnew;
            if (hhalf == 0) p_sh[w * 128 + kj * 4 + i] = pj;
        }

        // ctx += P^T @ V ; lane owns dims (2*lane, 2*lane+1)
        #pragma unroll 8
        for (int j = 0; j < 32; ++j) {
            const float4 p4 = *(const float4*)&p_sh[w * 128 + j * 4];
            const float2 vv = *(const float2*)&v_sh[j * 132 + 2 * lane];
            cx[0] += p4.x * vv.x; cy[0] += p4.x * vv.y;
            cx[1] += p4.y * vv.x; cy[1] += p4.y * vv.y;
            cx[2] += p4.z * vv.x; cy[2] += p4.z * vv.y;
            cx[3] += p4.w * vv.x; cy[3] += p4.w * vv.y;
        }
    }

    // combine p=0 and p=1: out = ctx0 - lam * ctx1
    float* comb = q_sh;   // reuse (2048 floats needed, q_sh has 4096)
    __syncthreads();
    if (p == 1) {
        #pragma unroll
        for (int i = 0; i < 4; ++i) {
            const float invl = 1.0f / lrow[i];
            float2 o; o.x = cx[i] * invl; o.y = cy[i] * invl;
            *(float2*)&comb[(slot * 4 + i) * 128 + 2 * lane] = o;
        }
    }
    __syncthreads();
    if (p == 0) {
        #pragma unroll
        for (int i = 0; i < 4; ++i) {
            const int r = rbase + i;
            const float invl = 1.0f / lrow[i];
            const float lamv = Lam[(size_t)(b * L_SEQ + r) * NH + h];
            const float2 c1 = *(const float2*)&comb[(slot * 4 + i) * 128 + 2 * lane];
            const float ox = cx[i] * invl - lamv * c1.x;
            const float oy = cy[i] * invl - lamv * c1.y;
            const uint pk = (uint)f2bf(ox) | ((uint)f2bf(oy) << 16);
            *(uint*)&OutB[(size_t)(b * L_SEQ + r) * D_MODEL + (size_t)h * DH + 2 * lane] = pk;
        }
    }
}

// ---------------------------------------------------------------------------
extern "C" void kernel_launch(void* const* d_in, const int* in_sizes, int n_in,
                              void* d_out, int out_size, void* d_ws, size_t ws_size,
                              hipStream_t stream)
{
    const float* x  = (const float*)d_in[0];
    const float* Wq = (const float*)d_in[1];
    const float* Wk = (const float*)d_in[2];
    const float* Wv = (const float*)d_in[3];
    const float* Wl = (const float*)d_in[4];
    const float* bl = (const float*)d_in[5];
    const float* Wo = (const float*)d_in[6];
    float* out = (float*)d_out;
    (void)ws_size; (void)in_sizes; (void)n_in; (void)out_size;

    ushort* ws   = (ushort*)d_ws;
    ushort* xb   = ws;                       // 4096x2048
    ushort* Qb16 = xb   + (size_t)8388608;   // 4096x4096
    ushort* Kb16 = Qb16 + (size_t)16777216;  // 4096x2048
    ushort* Vb16 = Kb16 + (size_t)8388608;   // 4096x2048
    ushort* Wqt  = Vb16 + (size_t)8388608;   // 4096x2048 (Wq^T)
    ushort* Wkt  = Wqt  + (size_t)8388608;   // 2048x2048
    ushort* Wvt  = Wkt  + (size_t)4194304;   // 2048x2048
    ushort* Wot  = Wvt  + (size_t)4194304;   // 2048x2048
    ushort* OutB = Wot  + (size_t)4194304;   // 4096x2048
    float*  LamB = (float*)(OutB + (size_t)8388608);  // 4096x16

    // dtype conversions
    cvt_bf16<<<4096, 256, 0, stream>>>(x, xb);
    transpose_cvt<<<dim3(128, 64), 256, 0, stream>>>(Wq, Wqt, 2048, 4096);
    transpose_cvt<<<dim3(64, 64), 256, 0, stream>>>(Wk, Wkt, 2048, 2048);
    transpose_cvt<<<dim3(64, 64), 256, 0, stream>>>(Wv, Wvt, 2048, 2048);
    transpose_cvt<<<dim3(64, 64), 256, 0, stream>>>(Wo, Wot, 2048, 2048);
    lam_kernel<<<256, 256, 0, stream>>>(x, Wl, bl, LamB);

    // projections (bf16 MFMA)
    gemm_bf16<1><<<dim3(32, 32), 256, 0, stream>>>(xb, Wqt, Qb16, M_ROWS, 4096, D_MODEL);
    gemm_bf16<1><<<dim3(16, 32), 256, 0, stream>>>(xb, Wkt, Kb16, M_ROWS, D_MODEL, D_MODEL);
    gemm_bf16<1><<<dim3(16, 32), 256, 0, stream>>>(xb, Wvt, Vb16, M_ROWS, D_MODEL, D_MODEL);

    // RoPE on q (32 head-pairs) and k (16 heads)
    rope_bf16<<<(M_ROWS * 32 * 64) / 256, 256, 0, stream>>>(Qb16, 32);
    rope_bf16<<<(M_ROWS * 16 * 64) / 256, 256, 0, stream>>>(Kb16, 16);

    // differential causal attention -> OutB (B, L, D) bf16
    attn_kernel<<<dim3(L_SEQ / 16, NH, 2), 512, 0, stream>>>(Qb16, Kb16, Vb16, LamB, OutB);

    // final projection (fp32 out)
    gemm_bf16<0><<<dim3(16, 32), 256, 0, stream>>>(OutB, Wot, out, M_ROWS, D_MODEL, D_MODEL);
}

// Round 3
// 827.210 us; speedup vs baseline: 6.5440x; 3.4117x over previous
//
#include <hip/hip_runtime.h>
#include <cstddef>
#include <cstdint>

#define L_SEQ 2048
#define D_MODEL 2048
#define NH 16
#define DH 128
#define M_ROWS 4096   // B * L

// ---------------------------------------------------------------------------
// bf16 helpers (storage type: ushort)
// ---------------------------------------------------------------------------
__device__ __forceinline__ ushort f2bf(float f) {
    union { float f; uint32_t u; } v; v.f = f;
    const uint32_t u = v.u;
    return (ushort)((u + 0x7fffu + ((u >> 16) & 1u)) >> 16);   // RNE
}
__device__ __forceinline__ float bf2f(ushort h) {
    union { uint32_t u; float f; } v; v.u = ((uint32_t)h) << 16; return v.f;
}

__device__ __forceinline__ void gld_lds16(const void* g, void* l) {
    __builtin_amdgcn_global_load_lds(
        (const __attribute__((address_space(1))) void*)g,
        (__attribute__((address_space(3))) void*)l, 16, 0, 0);
}

typedef __bf16  bf16x8 __attribute__((ext_vector_type(8)));
typedef float   f32x4  __attribute__((ext_vector_type(4)));

// ---------------------------------------------------------------------------
// fp32 -> bf16 elementwise (8 elems/thread)
// ---------------------------------------------------------------------------
__global__ __launch_bounds__(256) void cvt_bf16(
    const float* __restrict__ in, ushort* __restrict__ out)
{
    const int i = (blockIdx.x * 256 + threadIdx.x) * 8;
    const float4 a = *(const float4*)&in[i];
    const float4 b = *(const float4*)&in[i + 4];
    uint4 o;
    o.x = (uint)f2bf(a.x) | ((uint)f2bf(a.y) << 16);
    o.y = (uint)f2bf(a.z) | ((uint)f2bf(a.w) << 16);
    o.z = (uint)f2bf(b.x) | ((uint)f2bf(b.y) << 16);
    o.w = (uint)f2bf(b.z) | ((uint)f2bf(b.w) << 16);
    *(uint4*)&out[i] = o;
}

// ---------------------------------------------------------------------------
// W [K,N] fp32 -> Wt [N,K] bf16 (32x32 LDS tile transpose)
// ---------------------------------------------------------------------------
__global__ __launch_bounds__(256) void transpose_cvt(
    const float* __restrict__ W, ushort* __restrict__ Wt, int K, int N)
{
    __shared__ float tile[32][33];
    const int n0 = blockIdx.x * 32, k0 = blockIdx.y * 32;
    const int t = threadIdx.x;
    const int r = t >> 3;          // 0..31
    const int c4 = (t & 7) * 4;    // 0..28
    const float4 v = *(const float4*)&W[(size_t)(k0 + r) * N + n0 + c4];
    tile[r][c4 + 0] = v.x; tile[r][c4 + 1] = v.y;
    tile[r][c4 + 2] = v.z; tile[r][c4 + 3] = v.w;
    __syncthreads();
    ushort4 o;
    o.x = f2bf(tile[c4 + 0][r]);
    o.y = f2bf(tile[c4 + 1][r]);
    o.z = f2bf(tile[c4 + 2][r]);
    o.w = f2bf(tile[c4 + 3][r]);
    *(ushort4*)&Wt[(size_t)(n0 + r) * K + k0 + c4] = o;
}

// ---------------------------------------------------------------------------
// bf16 -> bf16 transpose of V: [4096 rows=(b,l)][2048 cols=(h,d)]
//   -> Vt [b][h][d][L] (so PV B-frags read contiguous keys)
// ---------------------------------------------------------------------------
__global__ __launch_bounds__(256) void vtrans(
    const ushort* __restrict__ V, ushort* __restrict__ Vt)
{
    __shared__ ushort tile[64][72];
    const int b  = blockIdx.z;
    const int l0 = blockIdx.x * 64;
    const int c0 = blockIdx.y * 64;
    const int t  = threadIdx.x;
    #pragma unroll
    for (int i = 0; i < 2; ++i) {
        const int s = t + i * 256;
        const int r = s >> 3, cq = (s & 7) * 8;
        *(uint4*)&tile[r][cq] =
            *(const uint4*)&V[(size_t)(b * 2048 + l0 + r) * 2048 + c0 + cq];
    }
    __syncthreads();
    #pragma unroll
    for (int i = 0; i < 2; ++i) {
        const int s  = t + i * 256;
        const int oc = s >> 3;          // col index within tile (0..63)
        const int lq = (s & 7) * 8;     // l offset
        ushort tmp[8];
        #pragma unroll
        for (int j = 0; j < 8; ++j) tmp[j] = tile[lq + j][oc];
        const int cg = c0 + oc;         // global col = h*128 + d
        *(uint4*)&Vt[((size_t)(b * 16 + (cg >> 7)) * 128 + (cg & 127)) * 2048
                     + l0 + lq] = *(uint4*)tmp;
    }
}

// ---------------------------------------------------------------------------
// bf16 MFMA GEMM (m97 recipe): C[M,N] = A[M,K] . Bt[N,K]^T
// ---------------------------------------------------------------------------
template <int OUT_BF16>
__global__ __launch_bounds__(256) void gemm_bf16(
    const ushort* __restrict__ A, const ushort* __restrict__ Bt,
    void* __restrict__ Cv, int M, int N, int K)
{
    __shared__ __align__(16) ushort As[128 * 32];
    __shared__ __align__(16) ushort Bs[128 * 32];
    const int bm = blockIdx.y * 128;
    const int bn = blockIdx.x * 128;
    const int t = threadIdx.x;
    const int w = t >> 6, lane = t & 63;
    const int wm = (w & 1) * 64;
    const int wn = (w >> 1) * 64;

    const int srow = t >> 2;
    const int scol = (t & 3) * 8;
    const ushort* Ag  = A  + (size_t)(bm + srow) * K + scol;
    const ushort* Ag2 = A  + (size_t)(bm + 64 + srow) * K + scol;
    const ushort* Bg  = Bt + (size_t)(bn + srow) * K + scol;
    const ushort* Bg2 = Bt + (size_t)(bn + 64 + srow) * K + scol;
    ushort* Asl  = &As[(size_t)t * 8];
    ushort* Asl2 = &As[(size_t)(t + 256) * 8];
    ushort* Bsl  = &Bs[(size_t)t * 8];
    ushort* Bsl2 = &Bs[(size_t)(t + 256) * 8];

    const int fr = lane & 15;
    const int fq = (lane >> 4) * 8;
    const ushort* Abase = &As[(size_t)(wm + fr) * 32 + fq];
    const ushort* Bbase = &Bs[(size_t)(wn + fr) * 32 + fq];

    f32x4 acc[4][4] = {};

    for (int k0 = 0; k0 < K; k0 += 32) {
        __syncthreads();
        gld_lds16(Ag + k0, Asl);
        gld_lds16(Ag2 + k0, Asl2);
        gld_lds16(Bg + k0, Bsl);
        gld_lds16(Bg2 + k0, Bsl2);
        __syncthreads();
        bf16x8 a[4], b[4];
        #pragma unroll
        for (int i = 0; i < 4; ++i) {
            a[i] = *(const bf16x8*)(Abase + (size_t)i * 16 * 32);
            b[i] = *(const bf16x8*)(Bbase + (size_t)i * 16 * 32);
        }
        #pragma unroll
        for (int mt = 0; mt < 4; ++mt)
            #pragma unroll
            for (int nt = 0; nt < 4; ++nt)
                acc[mt][nt] = __builtin_amdgcn_mfma_f32_16x16x32_bf16(
                    a[mt], b[nt], acc[mt][nt], 0, 0, 0);
    }

    const int crow = (lane >> 4) * 4;
    const int ccol = lane & 15;
    #pragma unroll
    for (int mt = 0; mt < 4; ++mt) {
        #pragma unroll
        for (int nt = 0; nt < 4; ++nt) {
            #pragma unroll
            for (int reg = 0; reg < 4; ++reg) {
                const size_t row = bm + wm + mt * 16 + crow + reg;
                const size_t col = bn + wn + nt * 16 + ccol;
                if (OUT_BF16) {
                    ((ushort*)Cv)[row * N + col] = f2bf(acc[mt][nt][reg]);
                } else {
                    ((float*)Cv)[row * N + col] = acc[mt][nt][reg];
                }
            }
        }
    }
}

// ---------------------------------------------------------------------------
// RoPE in-place on bf16
// ---------------------------------------------------------------------------
__global__ __launch_bounds__(256) void rope_bf16(ushort* __restrict__ T, int nheads)
{
    const int idx  = blockIdx.x * 256 + threadIdx.x;
    const int d    = idx & 63;
    const int tmp  = idx >> 6;
    const int head = tmp % nheads;
    const int row  = tmp / nheads;
    const int l    = row & (L_SEQ - 1);
    const float inv = powf(10000.0f, -(float)d * (1.0f / 64.0f));
    const float ang = (float)l * inv;
    float s, c;
    sincosf(ang, &s, &c);
    const size_t base = (size_t)row * ((size_t)nheads * DH) + (size_t)head * DH + d;
    const float t1 = bf2f(T[base]);
    const float t2 = bf2f(T[base + 64]);
    T[base]      = f2bf(t1 * c - t2 * s);
    T[base + 64] = f2bf(t2 * c + t1 * s);
}

// ---------------------------------------------------------------------------
// lam = sigmoid(x @ Wl + bl)
// ---------------------------------------------------------------------------
__global__ __launch_bounds__(256) void lam_kernel(
    const float* __restrict__ X, const float* __restrict__ Wl,
    const float* __restrict__ bl, float* __restrict__ Lam)
{
    const int idx = blockIdx.x * 256 + threadIdx.x;
    const int hh  = idx & 15;
    const int m   = idx >> 4;
    const float* xr = X + (size_t)m * D_MODEL;
    float acc = 0.0f;
    for (int d = 0; d < D_MODEL; d += 4) {
        const float4 xv = *(const float4*)&xr[d];
        acc += xv.x * Wl[(d + 0) * NH + hh];
        acc += xv.y * Wl[(d + 1) * NH + hh];
        acc += xv.z * Wl[(d + 2) * NH + hh];
        acc += xv.w * Wl[(d + 3) * NH + hh];
    }
    acc += bl[hh];
    Lam[idx] = 1.0f / (1.0f + expf(-acc));
}

// ---------------------------------------------------------------------------
// MFMA differential causal flash attention.
// Grid: (32 q-tiles, NH, B). Block: 512 thr = 8 waves.
//   wave w: p = w>>2 (0/1), rows r0w = q0 + (w&3)*16 .. +15.
// Per key-tile (64 keys): K [64][136] LDS, Vt [128][72] LDS (dims x keys),
// QK^T + online softmax + P (bf16, LDS round-trip) + PV, all 16x16x32 MFMA.
// p=1 ctx passed via LDS; p=0 writes out = ctx0 - lam*ctx1 (bf16).
// ---------------------------------------------------------------------------
__global__ __launch_bounds__(512) void attn_mfma(
    const ushort* __restrict__ Qb, const ushort* __restrict__ Kb,
    const ushort* __restrict__ Vtg, const float* __restrict__ Lam,
    ushort* __restrict__ OutB)
{
    __shared__ __align__(16) ushort lds[27136];   // 54272 B
    ushort* K_sh  = lds;            // [64][136]
    ushort* Vt_sh = lds + 8704;     // [128][72]
    ushort* P_sh  = lds + 17920;    // [8][16][72]

    const int h  = blockIdx.y;
    const int b  = blockIdx.z;
    const int qt = blockIdx.x;
    const int q0 = qt * 64;
    const int t  = threadIdx.x;
    const int w = t >> 6, lane = t & 63;
    const int colL = lane & 15, quad = lane >> 4;
    const int p = w >> 2;
    const int r0w = q0 + (w & 3) * 16;

    // Q fragments in registers: A[m=colL][k=quad*8+j + c*32]
    bf16x8 qf[4];
    {
        const ushort* Qr = Qb + (size_t)(b * 2048 + r0w + colL) * 4096
                         + (2 * h + p) * 128 + quad * 8;
        #pragma unroll
        for (int c = 0; c < 4; ++c)
            qf[c] = *(const bf16x8*)&Qr[c * 32];
    }

    f32x4 ctx[8] = {};
    float m_i[4] = {-1e30f, -1e30f, -1e30f, -1e30f};
    float l_i[4] = {0.f, 0.f, 0.f, 0.f};
    const float scale = 0.08838834764831845f;  // 1/sqrt(128)

    const ushort* Kgbase = Kb  + (size_t)(b * 2048) * 2048 + h * 128;
    const ushort* Vgbase = Vtg + (size_t)((b * 16 + h) * 128) * 2048;
    ushort* Pw = P_sh + w * (16 * 72);
    const int s0 = t, s1 = t + 512;

    for (int kt = 0; kt <= qt; ++kt) {
        const int kt0 = kt * 64;
        // global -> VGPR (padding-compatible staging)
        const uint4 kv0 = *(const uint4*)&Kgbase[(size_t)(kt0 + (s0 >> 4)) * 2048 + (s0 & 15) * 8];
        const uint4 kv1 = *(const uint4*)&Kgbase[(size_t)(kt0 + (s1 >> 4)) * 2048 + (s1 & 15) * 8];
        const uint4 vv0 = *(const uint4*)&Vgbase[(size_t)(s0 >> 3) * 2048 + kt0 + (s0 & 7) * 8];
        const uint4 vv1 = *(const uint4*)&Vgbase[(size_t)(s1 >> 3) * 2048 + kt0 + (s1 & 7) * 8];
        __syncthreads();
        *(uint4*)&K_sh[(s0 >> 4) * 136 + (s0 & 15) * 8] = kv0;
        *(uint4*)&K_sh[(s1 >> 4) * 136 + (s1 & 15) * 8] = kv1;
        *(uint4*)&Vt_sh[(s0 >> 3) * 72 + (s0 & 7) * 8]  = vv0;
        *(uint4*)&Vt_sh[(s1 >> 3) * 72 + (s1 & 7) * 8]  = vv1;
        __syncthreads();

        // ---- QK^T: scores[16 rows][64 keys] ----
        f32x4 sc[4] = {};
        #pragma unroll
        for (int c = 0; c < 4; ++c) {
            #pragma unroll
            for (int nt = 0; nt < 4; ++nt) {
                const bf16x8 kf = *(const bf16x8*)
                    &K_sh[(nt * 16 + colL) * 136 + c * 32 + quad * 8];
                sc[nt] = __builtin_amdgcn_mfma_f32_16x16x32_bf16(
                    qf[c], kf, sc[nt], 0, 0, 0);
            }
        }

        const bool need_mask = (kt0 + 63 > r0w);
        // ---- online softmax (rows = quad*4 + reg) ----
        #pragma unroll
        for (int reg = 0; reg < 4; ++reg) {
            const int row = r0w + quad * 4 + reg;
            float s[4];
            #pragma unroll
            for (int nt = 0; nt < 4; ++nt) {
                float v = sc[nt][reg] * scale;
                if (need_mask && (kt0 + nt * 16 + colL > row)) v = -1e9f;
                s[nt] = v;
            }
            float mx = fmaxf(fmaxf(s[0], s[1]), fmaxf(s[2], s[3]));
            #pragma unroll
            for (int off = 8; off >= 1; off >>= 1)
                mx = fmaxf(mx, __shfl_xor(mx, off));
            const float mnew  = fmaxf(m_i[reg], mx);
            const float alpha = __expf(m_i[reg] - mnew);
            float rs = 0.f;
            #pragma unroll
            for (int nt = 0; nt < 4; ++nt) {
                const float pv = __expf(s[nt] - mnew);
                s[nt] = pv;
                rs += pv;
            }
            #pragma unroll
            for (int off = 8; off >= 1; off >>= 1)
                rs += __shfl_xor(rs, off);
            l_i[reg] = l_i[reg] * alpha + rs;
            m_i[reg] = mnew;
            #pragma unroll
            for (int nt2 = 0; nt2 < 8; ++nt2)
                ctx[nt2][reg] *= alpha;
            #pragma unroll
            for (int nt = 0; nt < 4; ++nt)
                Pw[(quad * 4 + reg) * 72 + nt * 16 + colL] = f2bf(s[nt]);
        }

        // ---- PV: ctx[16 rows][128 dims] += P[16][64] . Vt[128][64]^T ----
        #pragma unroll
        for (int c2 = 0; c2 < 2; ++c2) {
            const bf16x8 pf = *(const bf16x8*)&Pw[colL * 72 + c2 * 32 + quad * 8];
            #pragma unroll
            for (int nt2 = 0; nt2 < 8; ++nt2) {
                const bf16x8 vf = *(const bf16x8*)
                    &Vt_sh[(nt2 * 16 + colL) * 72 + c2 * 32 + quad * 8];
                ctx[nt2] = __builtin_amdgcn_mfma_f32_16x16x32_bf16(
                    pf, vf, ctx[nt2], 0, 0, 0);
            }
        }
    }

    float invl[4];
    #pragma unroll
    for (int reg = 0; reg < 4; ++reg) invl[reg] = 1.0f / l_i[reg];

    // ---- differential combine through LDS ----
    float* comb = (float*)lds;   // [64][130] f32 = 33280 B (aliases K/Vt)
    __syncthreads();
    if (p == 1) {
        #pragma unroll
        for (int nt2 = 0; nt2 < 8; ++nt2)
            #pragma unroll
            for (int reg = 0; reg < 4; ++reg)
                comb[((w & 3) * 16 + quad * 4 + reg) * 130 + nt2 * 16 + colL]
                    = ctx[nt2][reg] * invl[reg];
    }
    __syncthreads();
    if (p == 0) {
        #pragma unroll
        for (int reg = 0; reg < 4; ++reg) {
            const int row = r0w + quad * 4 + reg;
            const float lamv = Lam[(size_t)(b * 2048 + row) * 16 + h];
            ushort* orow = OutB + (size_t)(b * 2048 + row) * 2048 + h * 128;
            #pragma unroll
            for (int nt2 = 0; nt2 < 8; ++nt2) {
                const float c1 =
                    comb[((w & 3) * 16 + quad * 4 + reg) * 130 + nt2 * 16 + colL];
                const float o = ctx[nt2][reg] * invl[reg] - lamv * c1;
                orow[nt2 * 16 + colL] = f2bf(o);
            }
        }
    }
}

// ---------------------------------------------------------------------------
extern "C" void kernel_launch(void* const* d_in, const int* in_sizes, int n_in,
                              void* d_out, int out_size, void* d_ws, size_t ws_size,
                              hipStream_t stream)
{
    const float* x  = (const float*)d_in[0];
    const float* Wq = (const float*)d_in[1];
    const float* Wk = (const float*)d_in[2];
    const float* Wv = (const float*)d_in[3];
    const float* Wl = (const float*)d_in[4];
    const float* bl = (const float*)d_in[5];
    const float* Wo = (const float*)d_in[6];
    float* out = (float*)d_out;
    (void)ws_size; (void)in_sizes; (void)n_in; (void)out_size;

    ushort* ws   = (ushort*)d_ws;
    ushort* xb   = ws;                       // 4096x2048
    ushort* Qb16 = xb   + (size_t)8388608;   // 4096x4096
    ushort* Kb16 = Qb16 + (size_t)16777216;  // 4096x2048
    ushort* Vb16 = Kb16 + (size_t)8388608;   // 4096x2048
    ushort* Vtg  = Vb16 + (size_t)8388608;   // 2x16x128x2048 (V^T)
    ushort* Wqt  = Vtg  + (size_t)8388608;   // 4096x2048 (Wq^T)
    ushort* Wkt  = Wqt  + (size_t)8388608;   // 2048x2048
    ushort* Wvt  = Wkt  + (size_t)4194304;   // 2048x2048
    ushort* Wot  = Wvt  + (size_t)4194304;   // 2048x2048
    ushort* OutB = Wot  + (size_t)4194304;   // 4096x2048
    float*  LamB = (float*)(OutB + (size_t)8388608);  // 4096x16

    // dtype conversions
    cvt_bf16<<<4096, 256, 0, stream>>>(x, xb);
    transpose_cvt<<<dim3(128, 64), 256, 0, stream>>>(Wq, Wqt, 2048, 4096);
    transpose_cvt<<<dim3(64, 64), 256, 0, stream>>>(Wk, Wkt, 2048, 2048);
    transpose_cvt<<<dim3(64, 64), 256, 0, stream>>>(Wv, Wvt, 2048, 2048);
    transpose_cvt<<<dim3(64, 64), 256, 0, stream>>>(Wo, Wot, 2048, 2048);
    lam_kernel<<<256, 256, 0, stream>>>(x, Wl, bl, LamB);

    // projections (bf16 MFMA)
    gemm_bf16<1><<<dim3(32, 32), 256, 0, stream>>>(xb, Wqt, Qb16, M_ROWS, 4096, D_MODEL);
    gemm_bf16<1><<<dim3(16, 32), 256, 0, stream>>>(xb, Wkt, Kb16, M_ROWS, D_MODEL, D_MODEL);
    gemm_bf16<1><<<dim3(16, 32), 256, 0, stream>>>(xb, Wvt, Vb16, M_ROWS, D_MODEL, D_MODEL);

    // RoPE on q (32 head-pairs) and k (16 heads)
    rope_bf16<<<(M_ROWS * 32 * 64) / 256, 256, 0, stream>>>(Qb16, 32);
    rope_bf16<<<(M_ROWS * 16 * 64) / 256, 256, 0, stream>>>(Kb16, 16);

    // V^T for MFMA PV fragments
    vtrans<<<dim3(32, 32, 2), 256, 0, stream>>>(Vb16, Vtg);

    // MFMA differential causal flash attention -> OutB (bf16)
    attn_mfma<<<dim3(32, NH, 2), 512, 0, stream>>>(Qb16, Kb16, Vtg, LamB, OutB);

    // final projection (fp32 out)
    gemm_bf16<0><<<dim3(16, 32), 256, 0, stream>>>(OutB, Wot, out, M_ROWS, D_MODEL, D_MODEL);
}

// Round 4
// 755.600 us; speedup vs baseline: 7.1642x; 1.0948x over previous
//
#include <hip/hip_runtime.h>
#include <cstddef>
#include <cstdint>

#define L_SEQ 2048
#define D_MODEL 2048
#define NH 16
#define DH 128
#define M_ROWS 4096   // B * L

// ---------------------------------------------------------------------------
// bf16 helpers (storage type: ushort)
// ---------------------------------------------------------------------------
__device__ __forceinline__ ushort f2bf(float f) {
    union { float f; uint32_t u; } v; v.f = f;
    const uint32_t u = v.u;
    return (ushort)((u + 0x7fffu + ((u >> 16) & 1u)) >> 16);   // RNE
}
__device__ __forceinline__ float bf2f(ushort h) {
    union { uint32_t u; float f; } v; v.u = ((uint32_t)h) << 16; return v.f;
}
__device__ __forceinline__ float2 bf2f2(uint32_t u) {
    union { uint32_t u; float f; } lo, hi;
    lo.u = u << 16; hi.u = u & 0xffff0000u;
    return make_float2(lo.f, hi.f);
}

__device__ __forceinline__ void gld_lds16(const void* g, void* l) {
    __builtin_amdgcn_global_load_lds(
        (const __attribute__((address_space(1))) void*)g,
        (__attribute__((address_space(3))) void*)l, 16, 0, 0);
}

typedef __bf16  bf16x8 __attribute__((ext_vector_type(8)));
typedef float   f32x4  __attribute__((ext_vector_type(4)));

// ---------------------------------------------------------------------------
// fp32 -> bf16 elementwise (8 elems/thread)
// ---------------------------------------------------------------------------
__global__ __launch_bounds__(256) void cvt_bf16(
    const float* __restrict__ in, ushort* __restrict__ out)
{
    const int i = (blockIdx.x * 256 + threadIdx.x) * 8;
    const float4 a = *(const float4*)&in[i];
    const float4 b = *(const float4*)&in[i + 4];
    uint4 o;
    o.x = (uint)f2bf(a.x) | ((uint)f2bf(a.y) << 16);
    o.y = (uint)f2bf(a.z) | ((uint)f2bf(a.w) << 16);
    o.z = (uint)f2bf(b.x) | ((uint)f2bf(b.y) << 16);
    o.w = (uint)f2bf(b.z) | ((uint)f2bf(b.w) << 16);
    *(uint4*)&out[i] = o;
}

// ---------------------------------------------------------------------------
// W [K,N] fp32 -> Wt [N,K] bf16 (32x32 LDS tile transpose)
// ---------------------------------------------------------------------------
__global__ __launch_bounds__(256) void transpose_cvt(
    const float* __restrict__ W, ushort* __restrict__ Wt, int K, int N)
{
    __shared__ float tile[32][33];
    const int n0 = blockIdx.x * 32, k0 = blockIdx.y * 32;
    const int t = threadIdx.x;
    const int r = t >> 3;          // 0..31
    const int c4 = (t & 7) * 4;    // 0..28
    const float4 v = *(const float4*)&W[(size_t)(k0 + r) * N + n0 + c4];
    tile[r][c4 + 0] = v.x; tile[r][c4 + 1] = v.y;
    tile[r][c4 + 2] = v.z; tile[r][c4 + 3] = v.w;
    __syncthreads();
    ushort4 o;
    o.x = f2bf(tile[c4 + 0][r]);
    o.y = f2bf(tile[c4 + 1][r]);
    o.z = f2bf(tile[c4 + 2][r]);
    o.w = f2bf(tile[c4 + 3][r]);
    *(ushort4*)&Wt[(size_t)(n0 + r) * K + k0 + c4] = o;
}

// ---------------------------------------------------------------------------
// RoPE cos/sin table: Rtab[l*64 + d] = {cos, sin}(l * 10000^(-d/64))
// ---------------------------------------------------------------------------
__global__ __launch_bounds__(256) void rope_table(float2* __restrict__ tab)
{
    const int i = blockIdx.x * 256 + threadIdx.x;   // 131072
    const int d = i & 63, l = i >> 6;
    const float inv = exp2f(-(float)d * 0.20762050593045857f); // log2(1e4)/64
    const float ang = (float)l * inv;
    float s, c;
    sincosf(ang, &s, &c);
    tab[i] = make_float2(c, s);
}

// ---------------------------------------------------------------------------
// K RoPE in-place on bf16 via table. One thread per (row, head, d-pair).
// ---------------------------------------------------------------------------
__global__ __launch_bounds__(256) void rope_k(
    ushort* __restrict__ T, const float2* __restrict__ tab)
{
    const int idx = blockIdx.x * 256 + threadIdx.x;  // 4096*16*32
    const int d2   = (idx & 31) * 2;
    const int head = (idx >> 5) & 15;
    const int row  = idx >> 9;
    const int l    = row & (L_SEQ - 1);
    const size_t base = (size_t)row * 2048 + head * 128 + d2;
    const uint a = *(const uint*)&T[base];
    const uint b = *(const uint*)&T[base + 64];
    const float2 t0 = bf2f2(a);   // d2, d2+1 (lo half)
    const float2 t1 = bf2f2(b);   // d2+64, d2+65
    const float2 cs0 = tab[l * 64 + d2];
    const float2 cs1 = tab[l * 64 + d2 + 1];
    const float o0x = t0.x * cs0.x - t1.x * cs0.y;
    const float o0y = t0.y * cs1.x - t1.y * cs1.y;
    const float o1x = t1.x * cs0.x + t0.x * cs0.y;
    const float o1y = t1.y * cs1.x + t0.y * cs1.y;
    *(uint*)&T[base]      = (uint)f2bf(o0x) | ((uint)f2bf(o0y) << 16);
    *(uint*)&T[base + 64] = (uint)f2bf(o1x) | ((uint)f2bf(o1y) << 16);
}

// ---------------------------------------------------------------------------
// bf16 MFMA GEMM (m97 recipe): C[M,N] = A[M,K] . Bt[N,K]^T
// MODE 0: f32 out ; MODE 1: bf16 out ; MODE 3: bf16 out transposed into
//   Vt[b][h][d][L] layout (rows = b*2048+l, cols = h*128+d), packed b64.
// ---------------------------------------------------------------------------
template <int MODE>
__global__ __launch_bounds__(256) void gemm_bf16(
    const ushort* __restrict__ A, const ushort* __restrict__ Bt,
    void* __restrict__ Cv, int M, int N, int K)
{
    __shared__ __align__(16) ushort As[128 * 32];
    __shared__ __align__(16) ushort Bs[128 * 32];
    const int bm = blockIdx.y * 128;
    const int bn = blockIdx.x * 128;
    const int t = threadIdx.x;
    const int w = t >> 6, lane = t & 63;
    const int wm = (w & 1) * 64;
    const int wn = (w >> 1) * 64;

    const int srow = t >> 2;
    const int scol = (t & 3) * 8;
    const ushort* Ag  = A  + (size_t)(bm + srow) * K + scol;
    const ushort* Ag2 = A  + (size_t)(bm + 64 + srow) * K + scol;
    const ushort* Bg  = Bt + (size_t)(bn + srow) * K + scol;
    const ushort* Bg2 = Bt + (size_t)(bn + 64 + srow) * K + scol;
    ushort* Asl  = &As[(size_t)t * 8];
    ushort* Asl2 = &As[(size_t)(t + 256) * 8];
    ushort* Bsl  = &Bs[(size_t)t * 8];
    ushort* Bsl2 = &Bs[(size_t)(t + 256) * 8];

    const int fr = lane & 15;
    const int fq = (lane >> 4) * 8;
    const ushort* Abase = &As[(size_t)(wm + fr) * 32 + fq];
    const ushort* Bbase = &Bs[(size_t)(wn + fr) * 32 + fq];

    f32x4 acc[4][4] = {};

    for (int k0 = 0; k0 < K; k0 += 32) {
        __syncthreads();
        gld_lds16(Ag + k0, Asl);
        gld_lds16(Ag2 + k0, Asl2);
        gld_lds16(Bg + k0, Bsl);
        gld_lds16(Bg2 + k0, Bsl2);
        __syncthreads();
        bf16x8 a[4], b[4];
        #pragma unroll
        for (int i = 0; i < 4; ++i) {
            a[i] = *(const bf16x8*)(Abase + (size_t)i * 16 * 32);
            b[i] = *(const bf16x8*)(Bbase + (size_t)i * 16 * 32);
        }
        #pragma unroll
        for (int mt = 0; mt < 4; ++mt)
            #pragma unroll
            for (int nt = 0; nt < 4; ++nt)
                acc[mt][nt] = __builtin_amdgcn_mfma_f32_16x16x32_bf16(
                    a[mt], b[nt], acc[mt][nt], 0, 0, 0);
    }

    const int crow = (lane >> 4) * 4;
    const int ccol = lane & 15;
    #pragma unroll
    for (int mt = 0; mt < 4; ++mt) {
        #pragma unroll
        for (int nt = 0; nt < 4; ++nt) {
            if (MODE == 3) {
                const size_t row = bm + wm + mt * 16 + crow;   // b*2048 + l
                const size_t col = bn + wn + nt * 16 + ccol;   // h*128 + d
                ushort4 o4;
                o4.x = f2bf(acc[mt][nt][0]); o4.y = f2bf(acc[mt][nt][1]);
                o4.z = f2bf(acc[mt][nt][2]); o4.w = f2bf(acc[mt][nt][3]);
                *(ushort4*)&((ushort*)Cv)[
                    ((row >> 11) * 16 + (col >> 7)) * (size_t)(128 * 2048)
                    + (col & 127) * 2048 + (row & 2047)] = o4;
            } else {
                #pragma unroll
                for (int reg = 0; reg < 4; ++reg) {
                    const size_t row = bm + wm + mt * 16 + crow + reg;
                    const size_t col = bn + wn + nt * 16 + ccol;
                    if (MODE == 1) {
                        ((ushort*)Cv)[row * N + col] = f2bf(acc[mt][nt][reg]);
                    } else {
                        ((float*)Cv)[row * N + col] = acc[mt][nt][reg];
                    }
                }
            }
        }
    }
}

// ---------------------------------------------------------------------------
// lam = sigmoid(x @ Wl + bl)
// ---------------------------------------------------------------------------
__global__ __launch_bounds__(256) void lam_kernel(
    const float* __restrict__ X, const float* __restrict__ Wl,
    const float* __restrict__ bl, float* __restrict__ Lam)
{
    const int idx = blockIdx.x * 256 + threadIdx.x;
    const int hh  = idx & 15;
    const int m   = idx >> 4;
    const float* xr = X + (size_t)m * D_MODEL;
    float acc = 0.0f;
    for (int d = 0; d < D_MODEL; d += 4) {
        const float4 xv = *(const float4*)&xr[d];
        acc += xv.x * Wl[(d + 0) * NH + hh];
        acc += xv.y * Wl[(d + 1) * NH + hh];
        acc += xv.z * Wl[(d + 2) * NH + hh];
        acc += xv.w * Wl[(d + 3) * NH + hh];
    }
    acc += bl[hh];
    Lam[idx] = 1.0f / (1.0f + expf(-acc));
}

// ---------------------------------------------------------------------------
// MFMA differential causal flash attention, v2.
// Grid: (16 pair-tiles, NH, B). Block: 256 thr = 4 waves = (p:2)x(slot:2).
// Each block processes q-tiles qt = 31-pt then qt = pt (33 key-tiles total,
// uniform across blocks). Wave handles 32 q-rows (2 groups of 16).
// Prefetch pipeline: next K/V tile loaded into VGPRs during compute.
// Q-RoPE fused into the fragment load (pairs d,d+64 = frag c, c+2).
// Softmax in exp2 domain. p=1 ctx passed via LDS; p=0 writes
// out = ctx0 - lam*ctx1 (bf16).
// ---------------------------------------------------------------------------
__global__ __launch_bounds__(256, 2) void attn_mfma(
    const ushort* __restrict__ Qb, const ushort* __restrict__ Kb,
    const ushort* __restrict__ Vtg, const float* __restrict__ Lam,
    const float2* __restrict__ Rtab, ushort* __restrict__ OutB)
{
    __shared__ __align__(16) ushort lds[27136];   // 54272 B
    ushort* K_sh  = lds;            // [64][136]
    ushort* Vt_sh = lds + 8704;     // [128][72]
    ushort* P_sh  = lds + 17920;    // 4 waves x [32][72]

    const int h  = blockIdx.y;
    const int b  = blockIdx.z;
    const int pt = blockIdx.x;
    const int t  = threadIdx.x;
    const int w = t >> 6, lane = t & 63;
    const int colL = lane & 15, quad = lane >> 4;
    const int p = w >> 1, slot = w & 1;
    ushort* Pw = P_sh + w * (32 * 72);

    const ushort* Kgbase = Kb  + (size_t)(b * 2048) * 2048 + h * 128;
    const ushort* Vgbase = Vtg + (size_t)((b * 16 + h) * 128) * 2048;
    const float scale2 = 0.12751744f;   // log2(e)/sqrt(128)

    for (int ph = 0; ph < 2; ++ph) {
        const int qt  = ph ? pt : 31 - pt;
        const int q0  = qt * 64;
        const int r0w = q0 + slot * 32;

        // ---- load Q frags + fused RoPE ----
        bf16x8 qf[2][4];
        #pragma unroll
        for (int g = 0; g < 2; ++g) {
            const int l = r0w + g * 16 + colL;
            const ushort* Qr = Qb + (size_t)(b * 2048 + l) * 4096
                             + (2 * h + p) * 128 + quad * 8;
            ushort raw[4][8];
            #pragma unroll
            for (int c = 0; c < 4; ++c)
                *(uint4*)raw[c] = *(const uint4*)&Qr[c * 32];
            const float2* tb = Rtab + l * 64 + quad * 8;
            ushort o[4][8];
            #pragma unroll
            for (int c = 0; c < 2; ++c)
                #pragma unroll
                for (int j = 0; j < 8; ++j) {
                    const float2 cs = tb[c * 32 + j];
                    const float a  = bf2f(raw[c][j]);
                    const float bb = bf2f(raw[c + 2][j]);
                    o[c][j]     = f2bf(a * cs.x - bb * cs.y);
                    o[c + 2][j] = f2bf(bb * cs.x + a * cs.y);
                }
            #pragma unroll
            for (int c = 0; c < 4; ++c)
                qf[g][c] = *(const bf16x8*)o[c];
        }

        f32x4 ctx[2][8] = {};
        float m2[2][4] = {{-1e30f,-1e30f,-1e30f,-1e30f},
                          {-1e30f,-1e30f,-1e30f,-1e30f}};
        float li[2][4] = {};

        // ---- prefetch tile 0 ----
        uint4 kvr[4], vvr[4];
        #pragma unroll
        for (int i = 0; i < 4; ++i) {
            const int c = t + i * 256;
            kvr[i] = *(const uint4*)&Kgbase[(size_t)(c >> 4) * 2048 + (c & 15) * 8];
            vvr[i] = *(const uint4*)&Vgbase[(size_t)(c >> 3) * 2048 + (c & 7) * 8];
        }

        for (int kt = 0; kt <= qt; ++kt) {
            const int kt0 = kt * 64;
            __syncthreads();
            #pragma unroll
            for (int i = 0; i < 4; ++i) {
                const int c = t + i * 256;
                *(uint4*)&K_sh[(c >> 4) * 136 + (c & 15) * 8] = kvr[i];
                *(uint4*)&Vt_sh[(c >> 3) * 72 + (c & 7) * 8]  = vvr[i];
            }
            __syncthreads();
            if (kt < qt) {
                const int nkt0 = kt0 + 64;
                #pragma unroll
                for (int i = 0; i < 4; ++i) {
                    const int c = t + i * 256;
                    kvr[i] = *(const uint4*)&Kgbase[(size_t)(nkt0 + (c >> 4)) * 2048 + (c & 15) * 8];
                    vvr[i] = *(const uint4*)&Vgbase[(size_t)(c >> 3) * 2048 + nkt0 + (c & 7) * 8];
                }
            }

            // ---- QK^T: 32 rows x 64 keys ----
            f32x4 sc2[2][4] = {};
            #pragma unroll
            for (int c = 0; c < 4; ++c)
                #pragma unroll
                for (int nt = 0; nt < 4; ++nt) {
                    const bf16x8 kf = *(const bf16x8*)
                        &K_sh[(nt * 16 + colL) * 136 + c * 32 + quad * 8];
                    sc2[0][nt] = __builtin_amdgcn_mfma_f32_16x16x32_bf16(
                        qf[0][c], kf, sc2[0][nt], 0, 0, 0);
                    sc2[1][nt] = __builtin_amdgcn_mfma_f32_16x16x32_bf16(
                        qf[1][c], kf, sc2[1][nt], 0, 0, 0);
                }

            const bool dmask = (kt == qt);
            // ---- online softmax (exp2 domain) ----
            #pragma unroll
            for (int g = 0; g < 2; ++g)
                #pragma unroll
                for (int reg = 0; reg < 4; ++reg) {
                    const int row = r0w + g * 16 + quad * 4 + reg;
                    float s[4];
                    #pragma unroll
                    for (int nt = 0; nt < 4; ++nt) {
                        float v = sc2[g][nt][reg] * scale2;
                        if (dmask && (kt0 + nt * 16 + colL > row)) v = -1e9f;
                        s[nt] = v;
                    }
                    float mx = fmaxf(fmaxf(s[0], s[1]), fmaxf(s[2], s[3]));
                    #pragma unroll
                    for (int off = 8; off >= 1; off >>= 1)
                        mx = fmaxf(mx, __shfl_xor(mx, off));
                    const float mnew  = fmaxf(m2[g][reg], mx);
                    const float alpha = exp2f(m2[g][reg] - mnew);
                    float rs = 0.f;
                    #pragma unroll
                    for (int nt = 0; nt < 4; ++nt) {
                        const float pv = exp2f(s[nt] - mnew);
                        s[nt] = pv;
                        rs += pv;
                    }
                    #pragma unroll
                    for (int off = 8; off >= 1; off >>= 1)
                        rs += __shfl_xor(rs, off);
                    li[g][reg] = li[g][reg] * alpha + rs;
                    m2[g][reg] = mnew;
                    #pragma unroll
                    for (int nt2 = 0; nt2 < 8; ++nt2)
                        ctx[g][nt2][reg] *= alpha;
                    #pragma unroll
                    for (int nt = 0; nt < 4; ++nt)
                        Pw[(g * 16 + quad * 4 + reg) * 72 + nt * 16 + colL]
                            = f2bf(s[nt]);
                }

            // ---- PV ----
            #pragma unroll
            for (int c2 = 0; c2 < 2; ++c2) {
                const bf16x8 pf0 = *(const bf16x8*)
                    &Pw[colL * 72 + c2 * 32 + quad * 8];
                const bf16x8 pf1 = *(const bf16x8*)
                    &Pw[(16 + colL) * 72 + c2 * 32 + quad * 8];
                #pragma unroll
                for (int nt2 = 0; nt2 < 8; ++nt2) {
                    const bf16x8 vf = *(const bf16x8*)
                        &Vt_sh[(nt2 * 16 + colL) * 72 + c2 * 32 + quad * 8];
                    ctx[0][nt2] = __builtin_amdgcn_mfma_f32_16x16x32_bf16(
                        pf0, vf, ctx[0][nt2], 0, 0, 0);
                    ctx[1][nt2] = __builtin_amdgcn_mfma_f32_16x16x32_bf16(
                        pf1, vf, ctx[1][nt2], 0, 0, 0);
                }
            }
        }

        float invl[2][4];
        #pragma unroll
        for (int g = 0; g < 2; ++g)
            #pragma unroll
            for (int reg = 0; reg < 4; ++reg)
                invl[g][reg] = 1.0f / li[g][reg];

        // ---- differential combine through LDS ----
        float* comb = (float*)lds;   // [64][130] f32 (aliases K/Vt staging)
        __syncthreads();
        if (p == 1) {
            #pragma unroll
            for (int g = 0; g < 2; ++g)
                #pragma unroll
                for (int nt2 = 0; nt2 < 8; ++nt2)
                    #pragma unroll
                    for (int reg = 0; reg < 4; ++reg)
                        comb[(slot * 32 + g * 16 + quad * 4 + reg) * 130
                             + nt2 * 16 + colL] = ctx[g][nt2][reg] * invl[g][reg];
        }
        __syncthreads();
        if (p == 0) {
            #pragma unroll
            for (int g = 0; g < 2; ++g)
                #pragma unroll
                for (int reg = 0; reg < 4; ++reg) {
                    const int row = r0w + g * 16 + quad * 4 + reg;
                    const float lamv = Lam[(size_t)(b * 2048 + row) * 16 + h];
                    ushort* orow = OutB + (size_t)(b * 2048 + row) * 2048 + h * 128;
                    #pragma unroll
                    for (int nt2 = 0; nt2 < 8; ++nt2) {
                        const float c1 = comb[(slot * 32 + g * 16 + quad * 4 + reg) * 130
                                              + nt2 * 16 + colL];
                        const float o = ctx[g][nt2][reg] * invl[g][reg] - lamv * c1;
                        orow[nt2 * 16 + colL] = f2bf(o);
                    }
                }
        }
        __syncthreads();   // protect comb before next phase re-stages
    }
}

// ---------------------------------------------------------------------------
extern "C" void kernel_launch(void* const* d_in, const int* in_sizes, int n_in,
                              void* d_out, int out_size, void* d_ws, size_t ws_size,
                              hipStream_t stream)
{
    const float* x  = (const float*)d_in[0];
    const float* Wq = (const float*)d_in[1];
    const float* Wk = (const float*)d_in[2];
    const float* Wv = (const float*)d_in[3];
    const float* Wl = (const float*)d_in[4];
    const float* bl = (const float*)d_in[5];
    const float* Wo = (const float*)d_in[6];
    float* out = (float*)d_out;
    (void)ws_size; (void)in_sizes; (void)n_in; (void)out_size;

    ushort* ws   = (ushort*)d_ws;
    ushort* xb   = ws;                       // 4096x2048
    ushort* Qb16 = xb   + (size_t)8388608;   // 4096x4096
    ushort* Kb16 = Qb16 + (size_t)16777216;  // 4096x2048
    ushort* Vtg  = Kb16 + (size_t)8388608;   // 2x16x128x2048 (V^T)
    ushort* Wqt  = Vtg  + (size_t)8388608;   // 4096x2048 (Wq^T)
    ushort* Wkt  = Wqt  + (size_t)8388608;   // 2048x2048
    ushort* Wvt  = Wkt  + (size_t)4194304;   // 2048x2048
    ushort* Wot  = Wvt  + (size_t)4194304;   // 2048x2048
    ushort* OutB = Wot  + (size_t)4194304;   // 4096x2048
    float*  LamB = (float*)(OutB + (size_t)8388608);  // 4096x16
    float2* Rtab = (float2*)(LamB + (size_t)65536);   // 2048x64

    // dtype conversions + tables
    cvt_bf16<<<4096, 256, 0, stream>>>(x, xb);
    transpose_cvt<<<dim3(128, 64), 256, 0, stream>>>(Wq, Wqt, 2048, 4096);
    transpose_cvt<<<dim3(64, 64), 256, 0, stream>>>(Wk, Wkt, 2048, 2048);
    transpose_cvt<<<dim3(64, 64), 256, 0, stream>>>(Wv, Wvt, 2048, 2048);
    transpose_cvt<<<dim3(64, 64), 256, 0, stream>>>(Wo, Wot, 2048, 2048);
    lam_kernel<<<256, 256, 0, stream>>>(x, Wl, bl, LamB);
    rope_table<<<512, 256, 0, stream>>>(Rtab);

    // projections (bf16 MFMA); V written directly transposed
    gemm_bf16<1><<<dim3(32, 32), 256, 0, stream>>>(xb, Wqt, Qb16, M_ROWS, 4096, D_MODEL);
    gemm_bf16<1><<<dim3(16, 32), 256, 0, stream>>>(xb, Wkt, Kb16, M_ROWS, D_MODEL, D_MODEL);
    gemm_bf16<3><<<dim3(16, 32), 256, 0, stream>>>(xb, Wvt, Vtg, M_ROWS, D_MODEL, D_MODEL);

    // RoPE on K (Q RoPE fused in attention)
    rope_k<<<8192, 256, 0, stream>>>(Kb16, Rtab);

    // MFMA differential causal flash attention -> OutB (bf16)
    attn_mfma<<<dim3(16, NH, 2), 256, 0, stream>>>(Qb16, Kb16, Vtg, LamB, Rtab, OutB);

    // final projection (fp32 out)
    gemm_bf16<0><<<dim3(16, 32), 256, 0, stream>>>(OutB, Wot, out, M_ROWS, D_MODEL, D_MODEL);
}